// Round 8
// baseline (31.215 us; speedup 1.0000x reference)
//
#include <hip/hip_runtime.h>
#include <math.h>

struct Pose {
    float M[9], Tt[3], pR[9], pt[3], gR[9], gt[3], qn;
};

__device__ __forceinline__ float smooth_l1f(float x, float y) {
    float d = fabsf(x - y);
    return d < 1.0f ? 0.5f * d * d : d - 0.5f;
}

// row-major 3x3 -> quaternion, matching the reference's branch selection
// (tr>0 -> case 0, else 1+argmax(diag) with first-max tie-break)
__device__ void mat2quat_dev(const float* R, float* q) {
    float R00=R[0],R01=R[1],R02=R[2];
    float R10=R[3],R11=R[4],R12=R[5];
    float R20=R[6],R21=R[7],R22=R[8];
    float tr = R00 + R11 + R22;
    float t;
    if (tr > 0.0f) {
        t = 1.0f + tr;
        q[0]=t; q[1]=R21-R12; q[2]=R02-R20; q[3]=R10-R01;
    } else {
        int sel = 1; float best = R00;
        if (R11 > best) { sel = 2; best = R11; }
        if (R22 > best) { sel = 3; }
        if (sel == 1)      { t = 1.0f+R00-R11-R22; q[0]=R21-R12; q[1]=t; q[2]=R01+R10; q[3]=R02+R20; }
        else if (sel == 2) { t = 1.0f-R00+R11-R22; q[0]=R02-R20; q[1]=R01+R10; q[2]=t; q[3]=R12+R21; }
        else               { t = 1.0f-R00-R11+R22; q[0]=R10-R01; q[1]=R02+R20; q[2]=R12+R21; q[3]=t; }
    }
    float s = 0.5f / sqrtf(fmaxf(t, 1e-12f));
    q[0]*=s; q[1]*=s; q[2]*=s; q[3]*=s;
}

// All the small per-batch matrix algebra: fused transform for the point loss
// (M = gR^T*pR - I, Tt = gR^T*(pt-gt)) plus intermediates for t/r/qn terms.
__device__ void compute_pose(int b,
                             const float* __restrict__ pred_t,
                             const float* __restrict__ pred_q,
                             const float* __restrict__ gtT,
                             const float* __restrict__ initT,
                             Pose& P)
{
    float tx=pred_t[b*3+0], ty=pred_t[b*3+1], tz=pred_t[b*3+2];
    float q0=pred_q[b*4+0], q1=pred_q[b*4+1], q2=pred_q[b*4+2], q3=pred_q[b*4+3];
    float nsq = q0*q0+q1*q1+q2*q2+q3*q3;
    P.qn = (nsq-1.0f)*(nsq-1.0f);
    float inv = rsqrtf(nsq);
    float w=q0*inv, x=q1*inv, y=q2*inv, z=q3*inv;
    float R[9];
    R[0]=1.0f-2.0f*(y*y+z*z); R[1]=2.0f*(x*y-w*z);      R[2]=2.0f*(x*z+w*y);
    R[3]=2.0f*(x*y+w*z);      R[4]=1.0f-2.0f*(x*x+z*z); R[5]=2.0f*(y*z-w*x);
    R[6]=2.0f*(x*z-w*y);      R[7]=2.0f*(y*z+w*x);      R[8]=1.0f-2.0f*(x*x+y*y);

    float iR[9], it[3];
    for (int i=0;i<3;i++){
        for (int j=0;j<3;j++){
            iR[i*3+j]=initT[b*16+i*4+j];
            P.gR[i*3+j]=gtT[b*16+i*4+j];
        }
        it[i]=initT[b*16+i*4+3];
        P.gt[i]=gtT[b*16+i*4+3];
    }
    // inv(T_pred) @ init : pR = R^T iR, pt = R^T (it - t)
    for (int i=0;i<3;i++){
        for (int j=0;j<3;j++)
            P.pR[i*3+j] = R[0+i]*iR[0+j] + R[3+i]*iR[3+j] + R[6+i]*iR[6+j];
        P.pt[i] = R[0+i]*(it[0]-tx) + R[3+i]*(it[1]-ty) + R[6+i]*(it[2]-tz);
    }
    // RT = inv(gt) @ [pR pt] : M = gR^T pR - I, Tt = gR^T (pt - gt)
    for (int i=0;i<3;i++){
        for (int j=0;j<3;j++)
            P.M[i*3+j] = P.gR[0+i]*P.pR[0+j] + P.gR[3+i]*P.pR[3+j] + P.gR[6+i]*P.pR[6+j];
        P.Tt[i] = P.gR[0+i]*(P.pt[0]-P.gt[0]) + P.gR[3+i]*(P.pt[1]-P.gt[1]) + P.gR[6+i]*(P.pt[2]-P.gt[2]);
    }
    P.M[0]-=1.0f; P.M[4]-=1.0f; P.M[8]-=1.0f;   // pts - pcs = M*p + Tt
}

// scalar (t/r/qn) loss terms for one batch, already divided by B
__device__ float scalar_terms(const Pose& P, int B) {
    float t_term = smooth_l1f(P.pt[0],P.gt[0]) + smooth_l1f(P.pt[1],P.gt[1])
                 + smooth_l1f(P.pt[2],P.gt[2]);
    float qp[4], qg[4];
    mat2quat_dev(P.pR,qp); mat2quat_dev(P.gR,qg);
    float dw  = qp[0]*qg[0] + qp[1]*qg[1] + qp[2]*qg[2] + qp[3]*qg[3];
    float cx  = qp[2]*qg[3]-qp[3]*qg[2];
    float cy  = qp[3]*qg[1]-qp[1]*qg[3];
    float cz  = qp[1]*qg[2]-qp[2]*qg[1];
    float dvx = -qp[0]*qg[1] + qg[0]*qp[1] - cx;
    float dvy = -qp[0]*qg[2] + qg[0]*qp[2] - cy;
    float dvz = -qp[0]*qg[3] + qg[0]*qp[3] - cz;
    float r_term = 2.0f*atan2f(sqrtf(dvx*dvx+dvy*dvy+dvz*dvz), fabsf(dw));
    return (1.0f*t_term + 0.5f*r_term + 0.5f*P.qn) / (float)B;
}

#define TP  1024  // points per tile
#define F4T 768   // float4s of pcs per tile (TP*3/4)

// Streaming kernel, 2-tile-deep register pipeline: stage(ti+2) is issued
// while computing tile ti, so the ds_write of tile ti+1 consumes loads that
// have had a FULL iteration (compute+barrier) to land. Two static register
// sets (set0/set1) alternate via a wave-uniform parity branch (no runtime
// indexing -> no scratch). Mask int4 never touches LDS. Compute reads LDS
// via 3x ds_read_b128 at 48B lane stride (all 32 banks, conflict-free).
// One barrier per tile. NOTE (R6 lesson): do NOT fuse the finish via a
// global atomic counter - 1536 same-line RMWs + per-block threadfence
// doubled total time on this chip.
__global__ __launch_bounds__(256) void pc_fused(const float* __restrict__ pcs,
                                                const int* __restrict__ mask,
                                                const float* __restrict__ pred_t,
                                                const float* __restrict__ pred_q,
                                                const float* __restrict__ gtT,
                                                const float* __restrict__ initT,
                                                float2* __restrict__ partS,
                                                float* __restrict__ scalarS,
                                                int N, int bpb, int chunk, int B)
{
    int b   = blockIdx.x / bpb;
    int blk = blockIdx.x - b*bpb;
    int t   = threadIdx.x;

    __shared__ float sMT[12];
    __shared__ float sP[2][F4T*4];   // 2 x 12 KB
    __shared__ float sE[4], sM[4];

    float esum = 0.0f, msum = 0.0f;
    int r0 = blk * chunk;
    if (r0 >= N) {   // defensive; not hit with current shapes
        if (t==0) partS[blockIdx.x] = make_float2(0.0f, 0.0f);
        return;
    }
    int my_pts = N - r0; if (my_pts > chunk) my_pts = chunk;   // multiple of 4
    int nt    = (my_pts + TP - 1) / TP;
    int my_f4 = (my_pts * 3) >> 2;
    int my_m4 = my_pts >> 2;

    const float4* pf4 = (const float4*)pcs  + ((size_t)b*N + r0)*3/4;
    const int4*   mi4 = (const int4*)  mask + ((size_t)b*N + r0)/4;

    // two in-flight register sets (static names)
    float4 a0, b0, c0; int4 m0;
    float4 a1, b1, c1; int4 m1;

    auto stage0 = [&](int ti) {
        int fb = ti * F4T;
        if (ti*TP + TP <= my_pts) {
            a0 = pf4[fb       + t];
            b0 = pf4[fb + 256 + t];
            c0 = pf4[fb + 512 + t];
            m0 = mi4[ti*256 + t];
        } else {
            int s0 = fb + t, s1 = fb + 256 + t, s2 = fb + 512 + t, sm = ti*256 + t;
            a0 = (s0 < my_f4) ? pf4[s0] : make_float4(0,0,0,0);
            b0 = (s1 < my_f4) ? pf4[s1] : make_float4(0,0,0,0);
            c0 = (s2 < my_f4) ? pf4[s2] : make_float4(0,0,0,0);
            m0 = (sm < my_m4) ? mi4[sm] : make_int4(0,0,0,0);
        }
    };
    auto stage1 = [&](int ti) {
        int fb = ti * F4T;
        if (ti*TP + TP <= my_pts) {
            a1 = pf4[fb       + t];
            b1 = pf4[fb + 256 + t];
            c1 = pf4[fb + 512 + t];
            m1 = mi4[ti*256 + t];
        } else {
            int s0 = fb + t, s1 = fb + 256 + t, s2 = fb + 512 + t, sm = ti*256 + t;
            a1 = (s0 < my_f4) ? pf4[s0] : make_float4(0,0,0,0);
            b1 = (s1 < my_f4) ? pf4[s1] : make_float4(0,0,0,0);
            c1 = (s2 < my_f4) ? pf4[s2] : make_float4(0,0,0,0);
            m1 = (sm < my_m4) ? mi4[sm] : make_int4(0,0,0,0);
        }
    };
    auto wr0 = [&](int buf) {   // write set0's pcs to LDS buffer
        float4* d = (float4*)sP[buf];
        d[t] = a0; d[t+256] = b0; d[t+512] = c0;
    };
    auto wr1 = [&](int buf) {
        float4* d = (float4*)sP[buf];
        d[t] = a1; d[t+256] = b1; d[t+512] = c1;
    };

    stage0(0);                       // tile0 loads in flight under pose calc
    if (t == 0) {
        Pose P;
        compute_pose(b, pred_t, pred_q, gtT, initT, P);
        #pragma unroll
        for (int k=0;k<9;k++) sMT[k]=P.M[k];
        sMT[9]=P.Tt[0]; sMT[10]=P.Tt[1]; sMT[11]=P.Tt[2];
        if (blk == 0) scalarS[b] = scalar_terms(P, B);   // hidden under streaming
    }
    __syncthreads();                 // sMT ready
    float m00=sMT[0], m01=sMT[1], m02=sMT[2];
    float m10=sMT[3], m11=sMT[4], m12=sMT[5];
    float m20=sMT[6], m21=sMT[7], m22=sMT[8];
    float t0 =sMT[9], t1 =sMT[10], t2 =sMT[11];
    wr0(0);                          // consume tile0 loads
    if (nt > 1) stage1(1);           // tile1 loads: a full prologue+tile0 to land
    __syncthreads();                 // buf0 ready

    for (int ti = 0; ti < nt; ti++) {
        int s = ti & 1;              // wave-uniform parity
        int4 cM;
        if (s == 0) { cM = m0; if (ti + 2 < nt) stage0(ti + 2); }
        else        { cM = m1; if (ti + 2 < nt) stage1(ti + 2); }

        const float4* sp4 = (const float4*)sP[s];
        float4 A = sp4[3*t], C = sp4[3*t+1], D = sp4[3*t+2];  // 3x ds_read_b128
        float px[4] = {A.x, A.w, C.z, D.y};
        float py[4] = {A.y, C.x, C.w, D.z};
        float pz[4] = {A.z, C.y, D.x, D.w};
        float mf[4] = {(float)cM.x, (float)cM.y, (float)cM.z, (float)cM.w};
        #pragma unroll
        for (int j=0;j<4;j++){
            float dx = fmaf(m00,px[j], fmaf(m01,py[j], fmaf(m02,pz[j], t0)));
            float dy = fmaf(m10,px[j], fmaf(m11,py[j], fmaf(m12,pz[j], t1)));
            float dz = fmaf(m20,px[j], fmaf(m21,py[j], fmaf(m22,pz[j], t2)));
            esum = fmaf(mf[j], sqrtf(fmaf(dx,dx, fmaf(dy,dy, dz*dz))), esum);
            msum += mf[j];
        }

        if (ti + 1 < nt) {           // write tile ti+1 (staged LAST iteration)
            if (s == 0) wr1(1); else wr0(0);
        }
        __syncthreads();             // one barrier per tile
    }

    for (int off=32; off>0; off>>=1){
        esum += __shfl_down(esum, off);
        msum += __shfl_down(msum, off);
    }
    int lane = t & 63, wid = t >> 6;
    if (lane==0){ sE[wid]=esum; sM[wid]=msum; }
    __syncthreads();
    if (t==0)
        partS[blockIdx.x] = make_float2(sE[0]+sE[1]+sE[2]+sE[3],
                                        sM[0]+sM[1]+sM[2]+sM[3]);
}

// Pure reduction: 32 threads per batch, bpb/32 contiguous float2 slots each
// (coalesced), shfl-reduce within the 32-group, then one thread combines
// with the precomputed scalar terms.
__global__ void finish_kernel(const float2* __restrict__ partS,
                              const float* __restrict__ scalarS,
                              float* __restrict__ out, int B, int bpb)
{
    int t = threadIdx.x;            // 256 threads
    int g = t >> 5, sub = t & 31;   // batch group, lane-in-group
    int per = bpb / 32;             // slots per thread (6 for bpb=192)
    __shared__ double sPC[8];

    float e = 0.0f, m = 0.0f;
    if (g < B) {
        const float2* base = partS + (size_t)g*bpb + sub*per;
        for (int k = 0; k < per; k++) { float2 v = base[k]; e += v.x; m += v.y; }
    }
    for (int off=16; off>0; off>>=1){
        e += __shfl_down(e, off, 32);
        m += __shfl_down(m, off, 32);
    }
    if (sub == 0 && g < B) sPC[g] = (double)e / (double)m;
    __syncthreads();
    if (t == 0) {
        double pc = 0.0; float sc = 0.0f;
        for (int b=0;b<B;b++){ pc += sPC[b]; sc += scalarS[b]; }
        out[0] = sc + 0.5f * (float)(pc / (double)B);
    }
}

extern "C" void kernel_launch(void* const* d_in, const int* in_sizes, int n_in,
                              void* d_out, int out_size, void* d_ws, size_t ws_size,
                              hipStream_t stream)
{
    const float* pred_t = (const float*)d_in[0];
    const float* pred_q = (const float*)d_in[1];
    const float* pcs    = (const float*)d_in[2];
    const float* gtT    = (const float*)d_in[3];
    const float* initT  = (const float*)d_in[4];
    const int*   mask   = (const int*)d_in[5];

    int B = in_sizes[0] / 3;
    int N = in_sizes[2] / (B * 3);

    int bpb   = 192;                                   // 6 blocks/CU at ~24.2 KB LDS
    int chunk = (((N + bpb - 1) / bpb) + 3) & ~3;      // points/block, mult of 4
    int grid  = B * bpb;                               // 1536 = exactly 6/CU

    float2* partS   = (float2*)d_ws;                   // [grid], always written
    float*  scalarS = (float*)(partS + grid);          // [B], always written
    float*  out     = (float*)d_out;

    pc_fused<<<grid, 256, 0, stream>>>(pcs, mask, pred_t, pred_q, gtT, initT,
                                       partS, scalarS, N, bpb, chunk, B);
    finish_kernel<<<1, 256, 0, stream>>>(partS, scalarS, out, B, bpb);
}

// Round 9
// 27.952 us; speedup vs baseline: 1.1167x; 1.1167x over previous
//
#include <hip/hip_runtime.h>
#include <math.h>

struct Pose {
    float M[9], Tt[3], pR[9], pt[3], gR[9], gt[3], qn;
};

__device__ __forceinline__ float smooth_l1f(float x, float y) {
    float d = fabsf(x - y);
    return d < 1.0f ? 0.5f * d * d : d - 0.5f;
}

// async global->LDS, 16B per lane (wave-uniform LDS base + lane*16; our
// layout is lane-linear so per-lane pointers are consistent with HW).
__device__ __forceinline__ void gload_lds16(const void* g, void* l) {
    __builtin_amdgcn_global_load_lds((const __attribute__((address_space(1))) void*)g,
                                     (__attribute__((address_space(3))) void*)l,
                                     16, 0, 0);
}

// row-major 3x3 -> quaternion, matching the reference's branch selection
// (tr>0 -> case 0, else 1+argmax(diag) with first-max tie-break)
__device__ void mat2quat_dev(const float* R, float* q) {
    float R00=R[0],R01=R[1],R02=R[2];
    float R10=R[3],R11=R[4],R12=R[5];
    float R20=R[6],R21=R[7],R22=R[8];
    float tr = R00 + R11 + R22;
    float t;
    if (tr > 0.0f) {
        t = 1.0f + tr;
        q[0]=t; q[1]=R21-R12; q[2]=R02-R20; q[3]=R10-R01;
    } else {
        int sel = 1; float best = R00;
        if (R11 > best) { sel = 2; best = R11; }
        if (R22 > best) { sel = 3; }
        if (sel == 1)      { t = 1.0f+R00-R11-R22; q[0]=R21-R12; q[1]=t; q[2]=R01+R10; q[3]=R02+R20; }
        else if (sel == 2) { t = 1.0f-R00+R11-R22; q[0]=R02-R20; q[1]=R01+R10; q[2]=t; q[3]=R12+R21; }
        else               { t = 1.0f-R00-R11+R22; q[0]=R10-R01; q[1]=R02+R20; q[2]=R12+R21; q[3]=t; }
    }
    float s = 0.5f / sqrtf(fmaxf(t, 1e-12f));
    q[0]*=s; q[1]*=s; q[2]*=s; q[3]*=s;
}

// All the small per-batch matrix algebra: fused transform for the point loss
// (M = gR^T*pR - I, Tt = gR^T*(pt-gt)) plus intermediates for t/r/qn terms.
__device__ void compute_pose(int b,
                             const float* __restrict__ pred_t,
                             const float* __restrict__ pred_q,
                             const float* __restrict__ gtT,
                             const float* __restrict__ initT,
                             Pose& P)
{
    float tx=pred_t[b*3+0], ty=pred_t[b*3+1], tz=pred_t[b*3+2];
    float q0=pred_q[b*4+0], q1=pred_q[b*4+1], q2=pred_q[b*4+2], q3=pred_q[b*4+3];
    float nsq = q0*q0+q1*q1+q2*q2+q3*q3;
    P.qn = (nsq-1.0f)*(nsq-1.0f);
    float inv = rsqrtf(nsq);
    float w=q0*inv, x=q1*inv, y=q2*inv, z=q3*inv;
    float R[9];
    R[0]=1.0f-2.0f*(y*y+z*z); R[1]=2.0f*(x*y-w*z);      R[2]=2.0f*(x*z+w*y);
    R[3]=2.0f*(x*y+w*z);      R[4]=1.0f-2.0f*(x*x+z*z); R[5]=2.0f*(y*z-w*x);
    R[6]=2.0f*(x*z-w*y);      R[7]=2.0f*(y*z+w*x);      R[8]=1.0f-2.0f*(x*x+y*y);

    float iR[9], it[3];
    for (int i=0;i<3;i++){
        for (int j=0;j<3;j++){
            iR[i*3+j]=initT[b*16+i*4+j];
            P.gR[i*3+j]=gtT[b*16+i*4+j];
        }
        it[i]=initT[b*16+i*4+3];
        P.gt[i]=gtT[b*16+i*4+3];
    }
    // inv(T_pred) @ init : pR = R^T iR, pt = R^T (it - t)
    for (int i=0;i<3;i++){
        for (int j=0;j<3;j++)
            P.pR[i*3+j] = R[0+i]*iR[0+j] + R[3+i]*iR[3+j] + R[6+i]*iR[6+j];
        P.pt[i] = R[0+i]*(it[0]-tx) + R[3+i]*(it[1]-ty) + R[6+i]*(it[2]-tz);
    }
    // RT = inv(gt) @ [pR pt] : M = gR^T pR - I, Tt = gR^T (pt - gt)
    for (int i=0;i<3;i++){
        for (int j=0;j<3;j++)
            P.M[i*3+j] = P.gR[0+i]*P.pR[0+j] + P.gR[3+i]*P.pR[3+j] + P.gR[6+i]*P.pR[6+j];
        P.Tt[i] = P.gR[0+i]*(P.pt[0]-P.gt[0]) + P.gR[3+i]*(P.pt[1]-P.gt[1]) + P.gR[6+i]*(P.pt[2]-P.gt[2]);
    }
    P.M[0]-=1.0f; P.M[4]-=1.0f; P.M[8]-=1.0f;   // pts - pcs = M*p + Tt
}

// scalar (t/r/qn) loss terms for one batch, already divided by B
__device__ float scalar_terms(const Pose& P, int B) {
    float t_term = smooth_l1f(P.pt[0],P.gt[0]) + smooth_l1f(P.pt[1],P.gt[1])
                 + smooth_l1f(P.pt[2],P.gt[2]);
    float qp[4], qg[4];
    mat2quat_dev(P.pR,qp); mat2quat_dev(P.gR,qg);
    float dw  = qp[0]*qg[0] + qp[1]*qg[1] + qp[2]*qg[2] + qp[3]*qg[3];
    float cx  = qp[2]*qg[3]-qp[3]*qg[2];
    float cy  = qp[3]*qg[1]-qp[1]*qg[3];
    float cz  = qp[1]*qg[2]-qp[2]*qg[1];
    float dvx = -qp[0]*qg[1] + qg[0]*qp[1] - cx;
    float dvy = -qp[0]*qg[2] + qg[0]*qp[2] - cy;
    float dvz = -qp[0]*qg[3] + qg[0]*qp[3] - cz;
    float r_term = 2.0f*atan2f(sqrtf(dvx*dvx+dvy*dvy+dvz*dvz), fabsf(dw));
    return (1.0f*t_term + 0.5f*r_term + 0.5f*P.qn) / (float)B;
}

#define TP  512   // points per tile
#define F4T 384   // float4s of pcs per tile (TP*3/4)

// Streaming kernel, async-staged: per 512-point tile, 2 global_load_lds
// (width 16) per thread stage pcs (384 f4) + mask (128 i4) straight into
// LDS - no VGPR round trip, no ds_write, threads never touch staging data.
// Double-buffered, one barrier per tile (the barrier's vmcnt drain is the
// buffer-ready handshake). Compute: stride-3 b32 LDS reads (gcd(3,32)=1,
// conflict-free, 0 conflicts measured in R7). Tail tiles: per-lane issue
// guards + cndmask validity selects (select discards any NaN from
// uninitialized LDS bit patterns). Occupancy lesson (R8): keep LDS small -
// TLP, not per-thread pipelining, hides latency here. R6 lesson: no
// atomic-counter fusion of the finish (same-line RMW storm doubled time).
__global__ __launch_bounds__(256) void pc_fused(const float* __restrict__ pcs,
                                                const int* __restrict__ mask,
                                                const float* __restrict__ pred_t,
                                                const float* __restrict__ pred_q,
                                                const float* __restrict__ gtT,
                                                const float* __restrict__ initT,
                                                float2* __restrict__ partS,
                                                float* __restrict__ scalarS,
                                                int N, int bpb, int chunk, int B)
{
    int b   = blockIdx.x / bpb;
    int blk = blockIdx.x - b*bpb;
    int t   = threadIdx.x;

    __shared__ float sMT[12];
    __shared__ float4 sBuf[2][512];   // [0..384): pcs f4, [384..512): mask i4; 2 x 8 KB
    __shared__ float sE[4], sM[4];

    int r0 = blk * chunk;
    if (r0 >= N) {   // defensive; not hit with current shapes
        if (t==0) partS[blockIdx.x] = make_float2(0.0f, 0.0f);
        return;
    }
    int my_pts = N - r0; if (my_pts > chunk) my_pts = chunk;   // multiple of 4
    int nt    = (my_pts + TP - 1) / TP;
    int my_f4 = (my_pts * 3) >> 2;
    int my_m4 = my_pts >> 2;

    const float4* pf4 = (const float4*)pcs  + ((size_t)b*N + r0)*3/4;
    const int4*   mi4 = (const int4*)  mask + ((size_t)b*N + r0)/4;

    // issue tile ti's async loads into buffer `buf` (2 per thread, balanced:
    // waves 0,1 -> pcs chunk2; waves 2,3 -> mask)
    auto stage = [&](int ti, int buf) {
        int fb = ti * F4T;
        if (ti*TP + TP <= my_pts) {          // full tile, no guards
            gload_lds16(pf4 + fb + t, &sBuf[buf][t]);
            if (t < 128) gload_lds16(pf4 + fb + 256 + t, &sBuf[buf][256 + t]);
            else         gload_lds16(mi4 + ti*128 + (t-128), &sBuf[buf][384 + (t-128)]);
        } else {                             // tail tile, per-lane guards
            if (fb + t < my_f4) gload_lds16(pf4 + fb + t, &sBuf[buf][t]);
            if (t < 128) {
                if (fb + 256 + t < my_f4)
                    gload_lds16(pf4 + fb + 256 + t, &sBuf[buf][256 + t]);
            } else {
                if (ti*128 + (t-128) < my_m4)
                    gload_lds16(mi4 + ti*128 + (t-128), &sBuf[buf][384 + (t-128)]);
            }
        }
    };

    stage(0, 0);                     // tile0 loads in flight under pose calc
    if (t == 0) {
        Pose P;
        compute_pose(b, pred_t, pred_q, gtT, initT, P);
        #pragma unroll
        for (int k=0;k<9;k++) sMT[k]=P.M[k];
        sMT[9]=P.Tt[0]; sMT[10]=P.Tt[1]; sMT[11]=P.Tt[2];
        if (blk == 0) scalarS[b] = scalar_terms(P, B);   // hidden under streaming
    }
    __syncthreads();                 // drains vmcnt -> buf0 + sMT ready
    float m00=sMT[0], m01=sMT[1], m02=sMT[2];
    float m10=sMT[3], m11=sMT[4], m12=sMT[5];
    float m20=sMT[6], m21=sMT[7], m22=sMT[8];
    float t0 =sMT[9], t1 =sMT[10], t2 =sMT[11];

    float esum = 0.0f, msum = 0.0f;
    for (int ti = 0; ti < nt; ti++) {
        int s = ti & 1;
        if (ti + 1 < nt) stage(ti + 1, s ^ 1);   // issue next tile early

        const float* sp = (const float*)&sBuf[s][0];     // 1536 floats
        const int*   sk = (const int*)  &sBuf[s][384];   // 512 ints
        int tb = ti * TP;
        #pragma unroll
        for (int k = 0; k < 2; k++) {
            int p = t + (k << 8);                // 0..511
            float x = sp[3*p], y = sp[3*p+1], z = sp[3*p+2];
            int   mi = sk[p];
            bool  v  = (tb + p) < my_pts;
            float mm = v ? (float)mi : 0.0f;     // select: stale LDS discarded
            float dx = fmaf(m00,x, fmaf(m01,y, fmaf(m02,z, t0)));
            float dy = fmaf(m10,x, fmaf(m11,y, fmaf(m12,z, t1)));
            float dz = fmaf(m20,x, fmaf(m21,y, fmaf(m22,z, t2)));
            float er = mm * sqrtf(fmaf(dx,dx, fmaf(dy,dy, dz*dz)));
            esum += v ? er : 0.0f;               // select kills NaN bits too
            msum += mm;
        }
        __syncthreads();             // one barrier per tile (vmcnt drain = handshake)
    }

    for (int off=32; off>0; off>>=1){
        esum += __shfl_down(esum, off);
        msum += __shfl_down(msum, off);
    }
    int lane = t & 63, wid = t >> 6;
    if (lane==0){ sE[wid]=esum; sM[wid]=msum; }
    __syncthreads();
    if (t==0)
        partS[blockIdx.x] = make_float2(sE[0]+sE[1]+sE[2]+sE[3],
                                        sM[0]+sM[1]+sM[2]+sM[3]);
}

// Pure reduction: 32 threads per batch, bpb/32 contiguous float2 slots each
// (coalesced), shfl-reduce within the 32-group, then one thread combines
// with the precomputed scalar terms.
__global__ void finish_kernel(const float2* __restrict__ partS,
                              const float* __restrict__ scalarS,
                              float* __restrict__ out, int B, int bpb)
{
    int t = threadIdx.x;            // 256 threads
    int g = t >> 5, sub = t & 31;   // batch group, lane-in-group
    int per = bpb / 32;             // slots per thread (8 for bpb=256)
    __shared__ double sPC[8];

    float e = 0.0f, m = 0.0f;
    if (g < B) {
        const float2* base = partS + (size_t)g*bpb + sub*per;
        for (int k = 0; k < per; k++) { float2 v = base[k]; e += v.x; m += v.y; }
    }
    for (int off=16; off>0; off>>=1){
        e += __shfl_down(e, off, 32);
        m += __shfl_down(m, off, 32);
    }
    if (sub == 0 && g < B) sPC[g] = (double)e / (double)m;
    __syncthreads();
    if (t == 0) {
        double pc = 0.0; float sc = 0.0f;
        for (int b=0;b<B;b++){ pc += sPC[b]; sc += scalarS[b]; }
        out[0] = sc + 0.5f * (float)(pc / (double)B);
    }
}

extern "C" void kernel_launch(void* const* d_in, const int* in_sizes, int n_in,
                              void* d_out, int out_size, void* d_ws, size_t ws_size,
                              hipStream_t stream)
{
    const float* pred_t = (const float*)d_in[0];
    const float* pred_q = (const float*)d_in[1];
    const float* pcs    = (const float*)d_in[2];
    const float* gtT    = (const float*)d_in[3];
    const float* initT  = (const float*)d_in[4];
    const int*   mask   = (const int*)d_in[5];

    int B = in_sizes[0] / 3;
    int N = in_sizes[2] / (B * 3);

    int bpb   = 256;                                   // 8 blocks/CU, ~16.5 KB LDS
    int chunk = (((N + bpb - 1) / bpb) + 3) & ~3;      // points/block, mult of 4
    int grid  = B * bpb;

    float2* partS   = (float2*)d_ws;                   // [grid], always written
    float*  scalarS = (float*)(partS + grid);          // [B], always written
    float*  out     = (float*)d_out;

    pc_fused<<<grid, 256, 0, stream>>>(pcs, mask, pred_t, pred_q, gtT, initT,
                                       partS, scalarS, N, bpb, chunk, B);
    finish_kernel<<<1, 256, 0, stream>>>(partS, scalarS, out, B, bpb);
}